// Round 4
// baseline (254.642 us; speedup 1.0000x reference)
//
#include <hip/hip_runtime.h>

// OneDilate: out[b,c,i,j] = 50 - 0.5 * sum_{10x10 clamped window} x
// Two-phase LDS-tile kernel.
//  Phase A: 512 threads cooperatively stage a 25x512 halo-clamped input tile
//           into LDS via 7 independent coalesced float4 loads per thread
//           (one latency exposure per block, not per row).
//  Phase B: per thread: 4 output rows x 4 cols. Horizontal 10-sums from 4
//           aligned float4 LDS reads per streamed row (lane-consecutive,
//           conflict-free), direct accumulation into 4 float4 accs (no ring).
// Round-3 lesson: register-streaming w/ depth-1 prefetch is latency-bound
// (VALU 12.5%, HBM 26%, occupancy 46% -- all idle together). Decouple.

#define IMG 512
#define OUTW 511
#define KS 10
#define MEAN 4
#define SUBB 16                  // output rows per block
#define TS (SUBB + KS - 1)       // 25 streamed rows per block
#define ROWF4 (IMG / 4)          // 128 float4 per row
#define NF4 (TS * ROWF4)         // 3200 float4 = 50 KiB LDS
#define NTHREADS 512
#define NLOAD ((NF4 + NTHREADS - 1) / NTHREADS)  // 7
#define NBANDS (IMG / SUBB)      // 32
#define NIMG 96                  // 32 * 3 images
#define NWG (NBANDS * NIMG)      // 3072 (divisible by 8 XCDs)
#define CPX (NWG / 8)            // 384 per XCD chunk

__global__ __launch_bounds__(NTHREADS, 6) void onedilate_kernel(
    const float* __restrict__ x, float* __restrict__ out)
{
    __shared__ float4 smem[NF4];

    // Bijective XCD-aware swizzle: each XCD gets a contiguous chunk of
    // (band, image) work -> 9-row vertical halo between neighbor bands
    // is L2-resident.
    const int lin = blockIdx.y * NBANDS + blockIdx.x;
    const int swz = (lin & 7) * CPX + (lin >> 3);
    const int bx  = swz & (NBANDS - 1);   // row band
    const int bc  = swz >> 5;             // image index (NBANDS == 32)

    const int tid = threadIdx.x;
    const int rb  = bx * SUBB;            // first output row of this block

    const float* __restrict__ xim = x + (size_t)bc * (IMG * IMG);
    float* __restrict__ oim = out + (size_t)bc * (OUTW * OUTW);

    // ---------------- Phase A: stage tile into LDS ----------------
    // idx -> (streamed row r = idx>>7, col-group c4 = idx&127); row clamped.
    float4 t[NLOAD];
#pragma unroll
    for (int k = 0; k < NLOAD; ++k) {
        const int idx = k * NTHREADS + tid;
        if (idx < NF4) {
            const int r  = idx >> 7;
            const int c4 = idx & (ROWF4 - 1);
            const int ri = min(max(rb - MEAN + r, 0), IMG - 1);
            t[k] = *(const float4*)(xim + (size_t)ri * IMG + c4 * 4);
        }
    }
#pragma unroll
    for (int k = 0; k < NLOAD; ++k) {
        const int idx = k * NTHREADS + tid;
        if (idx < NF4) smem[idx] = t[k];
    }
    __syncthreads();

    // ---------------- Phase B: compute from LDS ----------------
    const int j  = tid & 127;             // col group: output cols 4j..4j+3
    const int rg = tid >> 7;              // row group 0..3 (4 rows each)
    const int cbase = 4 * j;
    const int bl0 = max(cbase - 4, 0);        // only j=0 OOB-low
    const int bl2 = min(cbase + 4, IMG - 4);  // only j=127 OOB-high
    const int bl3 = min(cbase + 8, IMG - 4);  // j=126,127 OOB-high
    const bool lo0 = (cbase - 4 < 0);
    const bool hi2 = (cbase + 4 > IMG - 4);
    const bool hi3 = (cbase + 8 > IMG - 4);

    const float* sf = (const float*)smem;
    float4 a0 = make_float4(0.f, 0.f, 0.f, 0.f);
    float4 a1 = a0, a2 = a0, a3 = a0;

#define ACC4(A) { A.x += H.x; A.y += H.y; A.z += H.z; A.w += H.w; }

#pragma unroll
    for (int sl = 0; sl < 13; ++sl) {
        const int s = rg * 4 + sl;        // local streamed row in [0,24]
        const float* rp = sf + s * IMG;
        float4 v0 = *(const float4*)(rp + bl0);
        float4 v1 = *(const float4*)(rp + cbase);
        float4 v2 = *(const float4*)(rp + bl2);
        float4 v3 = *(const float4*)(rp + bl3);
        if (lo0) v0 = make_float4(v0.x, v0.x, v0.x, v0.x);  // replicate col 0
        if (hi2) v2 = make_float4(v2.w, v2.w, v2.w, v2.w);  // replicate col 511
        const float w12 = hi3 ? v3.w : v3.x;                // col min(4j+8,511)

        // Horizontal 10-sums for 4 outputs: tree sum + parallel sliding diffs.
        const float S = ((v0.x + v0.y) + (v0.z + v0.w))
                      + ((v1.x + v1.y) + (v1.z + v1.w))
                      + (v2.x + v2.y);
        const float d1  = v2.z - v0.x;
        const float d2  = v2.w - v0.y;
        const float d3  = w12  - v0.z;
        const float d12 = d1 + d2;
        float4 H;
        H.x = S;
        H.y = S + d1;
        H.z = S + d12;
        H.w = S + (d12 + d3);

        // Vertical windows (static after unroll): output ro sums sl in [ro, ro+9].
        if (sl <= 9)             ACC4(a0)
        if (sl >= 1 && sl <= 10) ACC4(a1)
        if (sl >= 2 && sl <= 11) ACC4(a2)
        if (sl >= 3)             ACC4(a3)
    }
#undef ACC4

    const int i0 = rb + rg * 4;
#define STORE(ro, A)                                                       \
    { const int i = i0 + (ro);                                             \
      if (i < OUTW) {                                                      \
          float* op = oim + (size_t)i * OUTW + cbase;                      \
          op[0] = fmaf(A.x, -0.5f, 50.0f);                                 \
          op[1] = fmaf(A.y, -0.5f, 50.0f);                                 \
          op[2] = fmaf(A.z, -0.5f, 50.0f);                                 \
          if (cbase + 3 < OUTW) op[3] = fmaf(A.w, -0.5f, 50.0f);           \
      } }
    STORE(0, a0)
    STORE(1, a1)
    STORE(2, a2)
    STORE(3, a3)
#undef STORE
}

extern "C" void kernel_launch(void* const* d_in, const int* in_sizes, int n_in,
                              void* d_out, int out_size, void* d_ws, size_t ws_size,
                              hipStream_t stream) {
    const float* x = (const float*)d_in[0];
    float* out = (float*)d_out;

    dim3 block(NTHREADS, 1, 1);
    dim3 grid(NBANDS, NIMG, 1);   // 32 x 96 = 3072 blocks
    onedilate_kernel<<<grid, block, 0, stream>>>(x, out);
}

// Round 6
// 175.900 us; speedup vs baseline: 1.4477x; 1.4477x over previous
//
#include <hip/hip_runtime.h>

// OneDilate: out[b,c,i,j] = 50 - 0.5 * sum_{10x10 clamped window} x
// Two-phase LDS-tile kernel, async staging.
//  Phase A: 512 threads stage a 25x512 halo-clamped input tile into LDS via
//           __builtin_amdgcn_global_load_lds(width=16): no VGPR round-trip,
//           all loads in flight at once, one vmcnt drain at the barrier.
//           (Round-4 lesson: reg-staged t[7] spilled -> WRITE 372MB, 131us.)
//  Phase B: per thread: 4 output rows x 4 cols. Horizontal 10-sums from 4
//           aligned float4 LDS reads per streamed row (lane-consecutive,
//           conflict-free), direct accumulation into 4 float4 accs.
// LDS layout is linear (exactly global_load_lds's wave-uniform base +
// lane*16 semantics, m104) -- do NOT pad.

#define IMG 512
#define OUTW 511
#define KS 10
#define MEAN 4
#define SUBB 16                  // output rows per block
#define TS (SUBB + KS - 1)       // 25 streamed rows per block
#define ROWF4 (IMG / 4)          // 128 float4 per row
#define NF4 (TS * ROWF4)         // 3200 float4 = 50 KiB LDS
#define NTHREADS 512
#define NBANDS (IMG / SUBB)      // 32
#define NIMG 96                  // 32 * 3 images
#define NWG (NBANDS * NIMG)      // 3072 (divisible by 8 XCDs)
#define CPX (NWG / 8)            // 384 per XCD chunk

__global__ __launch_bounds__(NTHREADS) void onedilate_kernel(
    const float* __restrict__ x, float* __restrict__ out)
{
    __shared__ float smemf[TS * IMG];   // 51200 B

    // Bijective XCD-aware swizzle: each XCD gets a contiguous chunk of
    // (band, image) work -> 9-row vertical halo between neighbor bands
    // is L2-resident.
    const int lin = blockIdx.y * NBANDS + blockIdx.x;
    const int swz = (lin & 7) * CPX + (lin >> 3);
    const int bx  = swz & (NBANDS - 1);   // row band
    const int bc  = swz >> 5;             // image index (NBANDS == 32)

    const int tid = threadIdx.x;
    const int rb  = bx * SUBB;            // first output row of this block

    const float* __restrict__ xim = x + (size_t)bc * (IMG * IMG);
    float* __restrict__ oim = out + (size_t)bc * (OUTW * OUTW);

    // ---------------- Phase A: async stage tile into LDS ----------------
    // idx -> (streamed row r = idx>>7, col-group c4 = idx&127); row clamped.
    // LDS byte offset = idx*16: linear in tid -> matches HW lane*16 layout.
#define STAGE(idx_)                                                        \
    {                                                                      \
        const int r_  = (idx_) >> 7;                                       \
        const int c4_ = (idx_) & (ROWF4 - 1);                              \
        const int ri_ = min(max(rb - MEAN + r_, 0), IMG - 1);              \
        __builtin_amdgcn_global_load_lds(                                  \
            (const __attribute__((address_space(1))) void*)                \
                (xim + (size_t)ri_ * IMG + c4_ * 4),                       \
            (__attribute__((address_space(3))) void*)(smemf + (idx_) * 4), \
            16, 0, 0);                                                     \
    }
#pragma unroll
    for (int k = 0; k < 6; ++k) STAGE(k * NTHREADS + tid)
    if (tid < (NF4 - 6 * NTHREADS)) STAGE(6 * NTHREADS + tid)  // wave-uniform
#undef STAGE
    __syncthreads();   // drains vmcnt for the global_load_lds queue

    // ---------------- Phase B: compute from LDS ----------------
    const int j  = tid & 127;             // col group: output cols 4j..4j+3
    const int rg = tid >> 7;              // row group 0..3 (4 rows each)
    const int cbase = 4 * j;
    const int bl0 = max(cbase - 4, 0);        // only j=0 OOB-low
    const int bl2 = min(cbase + 4, IMG - 4);  // only j=127 OOB-high
    const int bl3 = min(cbase + 8, IMG - 4);  // j=126,127 OOB-high
    const bool lo0 = (cbase - 4 < 0);
    const bool hi2 = (cbase + 4 > IMG - 4);
    const bool hi3 = (cbase + 8 > IMG - 4);

    const float* sf = smemf;
    float4 a0 = make_float4(0.f, 0.f, 0.f, 0.f);
    float4 a1 = a0, a2 = a0, a3 = a0;

#define ACC4(A) { A.x += H.x; A.y += H.y; A.z += H.z; A.w += H.w; }

#pragma unroll
    for (int sl = 0; sl < 13; ++sl) {
        const int s = rg * 4 + sl;        // local streamed row in [0,24]
        const float* rp = sf + s * IMG;
        float4 v0 = *(const float4*)(rp + bl0);
        float4 v1 = *(const float4*)(rp + cbase);
        float4 v2 = *(const float4*)(rp + bl2);
        float4 v3 = *(const float4*)(rp + bl3);
        if (lo0) v0 = make_float4(v0.x, v0.x, v0.x, v0.x);  // replicate col 0
        if (hi2) v2 = make_float4(v2.w, v2.w, v2.w, v2.w);  // replicate col 511
        const float w12 = hi3 ? v3.w : v3.x;                // col min(4j+8,511)

        // Horizontal 10-sums for 4 outputs: tree sum + parallel sliding diffs.
        const float S = ((v0.x + v0.y) + (v0.z + v0.w))
                      + ((v1.x + v1.y) + (v1.z + v1.w))
                      + (v2.x + v2.y);
        const float d1  = v2.z - v0.x;
        const float d2  = v2.w - v0.y;
        const float d3  = w12  - v0.z;
        const float d12 = d1 + d2;
        float4 H;
        H.x = S;
        H.y = S + d1;
        H.z = S + d12;
        H.w = S + (d12 + d3);

        // Vertical windows (static after unroll): output ro sums sl in [ro, ro+9].
        if (sl <= 9)             ACC4(a0)
        if (sl >= 1 && sl <= 10) ACC4(a1)
        if (sl >= 2 && sl <= 11) ACC4(a2)
        if (sl >= 3)             ACC4(a3)
    }
#undef ACC4

    const int i0 = rb + rg * 4;
#define STORE(ro, A)                                                       \
    { const int i = i0 + (ro);                                             \
      if (i < OUTW) {                                                      \
          float* op = oim + (size_t)i * OUTW + cbase;                      \
          op[0] = fmaf(A.x, -0.5f, 50.0f);                                 \
          op[1] = fmaf(A.y, -0.5f, 50.0f);                                 \
          op[2] = fmaf(A.z, -0.5f, 50.0f);                                 \
          if (cbase + 3 < OUTW) op[3] = fmaf(A.w, -0.5f, 50.0f);           \
      } }
    STORE(0, a0)
    STORE(1, a1)
    STORE(2, a2)
    STORE(3, a3)
#undef STORE
}

extern "C" void kernel_launch(void* const* d_in, const int* in_sizes, int n_in,
                              void* d_out, int out_size, void* d_ws, size_t ws_size,
                              hipStream_t stream) {
    const float* x = (const float*)d_in[0];
    float* out = (float*)d_out;

    dim3 block(NTHREADS, 1, 1);
    dim3 grid(NBANDS, NIMG, 1);   // 32 x 96 = 3072 blocks
    onedilate_kernel<<<grid, block, 0, stream>>>(x, out);
}